// Round 6
// baseline (62347.772 us; speedup 1.0000x reference)
//
#include <hip/hip_runtime.h>

#define NN    500
#define TT    20000
#define NPAD  512
#define NBLK  8
#define NROW  64        // padded rows per block
#define TPB   1024
#define RPT   2         // rows per thread
#define CPT   16        // cols per thread (strided by 32)
#define DTC   0.05f
#define SQDTC 0.22360679774997896f

typedef unsigned int u32x4 __attribute__((ext_vector_type(4)));

// ---------------------------------------------------------------------------
// Fully-coherent 16B accessors (sc0 sc1). Packet layout (x, tag, y, tag):
// each 8B half carries one data word + one tag copy.
// ---------------------------------------------------------------------------
__device__ __forceinline__ void store_coh_u128(u32x4* p, u32x4 v) {
    asm volatile("global_store_dwordx4 %0, %1, off sc0 sc1" :: "v"(p), "v"(v) : "memory");
}
__device__ __forceinline__ u32x4 load_coh_u128(const u32x4* p) {
    u32x4 v;
    asm volatile("global_load_dwordx4 %0, %1, off sc0 sc1\n\t"
                 "s_waitcnt vmcnt(0)" : "=v"(v) : "v"(p) : "memory");
    return v;
}

// ws layout: pub[2][NPAD] of u32x4 = 16 KB
__global__ __launch_bounds__(1024) void hopf_init_ws(u32x4* pub) {
    int i = blockIdx.x * blockDim.x + threadIdx.x;
    if (i < 2 * NPAD) pub[i] = (u32x4){0u, 0u, 0u, 0u};
}

__global__ __launch_bounds__(TPB) void hopf_main(
    const float* __restrict__ sc, const float* __restrict__ x0,
    const float* __restrict__ y0, const float* __restrict__ aa,
    const float* __restrict__ om, const float* __restrict__ noise,
    const float* __restrict__ gg, float* __restrict__ out,
    u32x4* __restrict__ pub)
{
    const int tid  = threadIdx.x;
    const int blk  = blockIdx.x;
    const int cgrp = tid & 31;       // 32 column groups
    const int rgrp = tid >> 5;       // 32 row groups of RPT rows
    const int r0   = blk * NROW + rgrp * RPT;   // padded global row base

    __shared__ __align__(16) float2 xy[2][NPAD]; // double-buffered state

    // ---- sc slice -> registers.  col(c) = cgrp + 32*c ----
    float scr[RPT][CPT];
#pragma unroll
    for (int r = 0; r < RPT; ++r) {
        int row = r0 + r;
#pragma unroll
        for (int c = 0; c < CPT; ++c) {
            int col = cgrp + 32 * c;
            scr[r][c] = (row < NN && col < NN) ? sc[row * NN + col] : 0.0f;
        }
    }

    // ---- deg per row ----
    float dsum[RPT];
#pragma unroll
    for (int r = 0; r < RPT; ++r) {
        float s = 0.f;
#pragma unroll
        for (int c = 0; c < CPT; ++c) s += scr[r][c];
        dsum[r] = s;
    }
#pragma unroll
    for (int m = 16; m >= 1; m >>= 1) {
#pragma unroll
        for (int r = 0; r < RPT; ++r) dsum[r] += __shfl_xor(dsum[r], m, 32);
    }

    // ---- pin the sc slice (optimizer cannot demote/rematerialize) ----
#pragma unroll
    for (int r = 0; r < RPT; ++r)
#pragma unroll
        for (int c = 0; c < CPT; ++c)
            asm volatile("" : "+v"(scr[r][c]));

    // ---- per-finalize-lane constants (lanes cgrp<RPT own row r0+cgrp) ----
    float a_i = 0.f, om_i = 0.f, deg_i = 0.f;
    int myrow = -1;
    if (cgrp < RPT) {
        int row = r0 + cgrp;
        deg_i = (cgrp == 0) ? dsum[0] : dsum[1];
        if (row < NN) { myrow = row; a_i = aa[row]; om_i = om[row]; }
    }
    const float g = gg[0];

    // ---- initial state into LDS (pad slots stay zero in both buffers) ----
    xy[0][tid < NPAD ? tid : 0] = make_float2(0.f, 0.f);
    xy[1][tid < NPAD ? tid : 0] = make_float2(0.f, 0.f);
    __syncthreads();
    if (tid < NN) xy[0][tid] = make_float2(x0[tid], y0[tid]);
    __syncthreads();

    // prefetched noise for step 0
    float2 nz = make_float2(0.f, 0.f);
    if (myrow >= 0) nz = *(const float2*)(noise + 2 * (size_t)myrow);

    for (int t = 0; t < TT; ++t) {
        const int p = t & 1;
        // prefetch next step's noise (hidden under the matvec)
        float2 nz_next = make_float2(0.f, 0.f);
        if (myrow >= 0 && t + 1 < TT)
            nz_next = *(const float2*)(noise + (size_t)(t + 1) * (2 * NN) + 2 * (size_t)myrow);

        // ---- partial matvec: 2 rows x 16 strided cols per thread ----
        float2 acc[RPT];
#pragma unroll
        for (int r = 0; r < RPT; ++r) acc[r] = make_float2(0.f, 0.f);
#pragma unroll
        for (int c = 0; c < CPT; ++c) {
            float2 w = xy[p][cgrp + 32 * c];
#pragma unroll
            for (int r = 0; r < RPT; ++r) {
                acc[r].x += scr[r][c] * w.x;
                acc[r].y += scr[r][c] * w.y;
            }
        }
        // ---- reduce across the 32 column-group lanes ----
#pragma unroll
        for (int m = 16; m >= 1; m >>= 1) {
#pragma unroll
            for (int r = 0; r < RPT; ++r) {
                acc[r].x += __shfl_xor(acc[r].x, m, 32);
                acc[r].y += __shfl_xor(acc[r].y, m, 32);
            }
        }

        // ---- finalize + publish tagged 16B packet (lanes cgrp<RPT) ----
        if (myrow >= 0) {
            float sx = (cgrp == 0) ? acc[0].x : acc[1].x;
            float sy = (cgrp == 0) ? acc[0].y : acc[1].y;
            float2 cur = xy[p][myrow];
            float r2 = cur.x * cur.x + cur.y * cur.y;
            float cx = sx - deg_i * cur.x;
            float cy = sy - deg_i * cur.y;
            float dx = (a_i - r2) * cur.x - om_i * cur.y + g * cx;
            float dy = (a_i - r2) * cur.y + om_i * cur.x + g * cy;
            float xn = cur.x + DTC * dx + SQDTC * nz.x;
            float yn = cur.y + DTC * dy + SQDTC * nz.y;
            u32x4 pkt = { __float_as_uint(xn), (unsigned)(t + 1),
                          __float_as_uint(yn), (unsigned)(t + 1) };
            store_coh_u128(&pub[(size_t)p * NPAD + myrow], pkt);
            out[(size_t)t * NN + myrow] = xn;
        }
        nz = nz_next;

        if (t == TT - 1) break;   // uniform across grid

        // ---- gather: pipelined 2-deep poll of own tagged slot ----
        if (tid < NN) {
            const u32x4* slot = &pub[(size_t)p * NPAD + tid];
            const int need = t + 1;
            u32x4 va;
            // two outstanding loads to the SAME dest quad; register writes
            // complete in issue order, so under vmcnt(1) va holds the
            // second-newest load's result -> poll period ~ RTT/2.
            asm volatile("global_load_dwordx4 %0, %1, off sc0 sc1\n\t"
                         "global_load_dwordx4 %0, %1, off sc0 sc1"
                         : "=v"(va) : "v"(slot) : "memory");
            for (;;) {
                asm volatile("s_waitcnt vmcnt(1)" ::: "memory");
                __builtin_amdgcn_sched_barrier(0);
                if ((int)va.y >= need && (int)va.w >= need) break;
                asm volatile("global_load_dwordx4 %0, %1, off sc0 sc1"
                             : "+v"(va) : "v"(slot) : "memory");
            }
            // drain the still-in-flight load (it overwrites va); service
            // order isn't guaranteed, so re-check and repair if stale.
            asm volatile("s_waitcnt vmcnt(0)" ::: "memory");
            __builtin_amdgcn_sched_barrier(0);
            if ((int)va.y < need || (int)va.w < need) va = load_coh_u128(slot);
            xy[p ^ 1][tid] = make_float2(__uint_as_float(va.x), __uint_as_float(va.z));
        }
        __syncthreads();
    }
}

extern "C" void kernel_launch(void* const* d_in, const int* in_sizes, int n_in,
                              void* d_out, int out_size, void* d_ws, size_t ws_size,
                              hipStream_t stream) {
    const float* sc = (const float*)d_in[0];
    const float* x0 = (const float*)d_in[1];
    const float* y0 = (const float*)d_in[2];
    const float* aa = (const float*)d_in[3];
    const float* om = (const float*)d_in[4];
    const float* nz = (const float*)d_in[5];
    const float* gg = (const float*)d_in[6];
    float* out = (float*)d_out;

    u32x4* pub = (u32x4*)d_ws;   // 2*NPAD*16 = 16 KB

    hipLaunchKernelGGL(hopf_init_ws, dim3(1), dim3(1024), 0, stream, pub);
    hipLaunchKernelGGL(hopf_main, dim3(NBLK), dim3(TPB), 0, stream,
                       sc, x0, y0, aa, om, nz, gg, out, pub);
}

// Round 7
// 47277.271 us; speedup vs baseline: 1.3188x; 1.3188x over previous
//
#include <hip/hip_runtime.h>

#define NN    500
#define TT    20000
#define NPAD  512
#define NBLK  8
#define NROW  64        // padded rows per block
#define TPB   512
#define RPT   4         // rows per thread
#define CPT   16        // cols per thread (strided by 32)
#define CHUNK 64        // noise steps staged in LDS per bulk load
#define DTC   0.05f
#define SQDTC 0.22360679774997896f

typedef unsigned int u32x4 __attribute__((ext_vector_type(4)));

// ---------------------------------------------------------------------------
// Fully-coherent 16B accessors (sc0 sc1). Packet layout (x, tag, y, tag):
// each 8B half carries one data word + one tag copy.
// ---------------------------------------------------------------------------
__device__ __forceinline__ void store_coh_u128(u32x4* p, u32x4 v) {
    asm volatile("global_store_dwordx4 %0, %1, off sc0 sc1" :: "v"(p), "v"(v) : "memory");
}
__device__ __forceinline__ u32x4 load_coh_u128(const u32x4* p) {
    u32x4 v;
    asm volatile("global_load_dwordx4 %0, %1, off sc0 sc1\n\t"
                 "s_waitcnt vmcnt(0)" : "=v"(v) : "v"(p) : "memory");
    return v;
}

// ws layout: pub[2][NPAD] of u32x4 = 16 KB
__global__ __launch_bounds__(1024) void hopf_init_ws(u32x4* pub) {
    int i = blockIdx.x * blockDim.x + threadIdx.x;
    if (i < 2 * NPAD) pub[i] = (u32x4){0u, 0u, 0u, 0u};
}

// Stage CHUNK steps of this block's noise rows into nbuf (float2 [CHUNK][64]).
// Thread tid: step cb0 + (tid>>3), rows 8*(tid&7)+2i .. +1  (4x16B coalesced).
// Caller must __syncthreads() before nbuf is read.
__device__ __forceinline__ void load_noise_chunk(const float* noise, int blk, int tid,
                                                 int cb0, float2 (*nbuf)[64]) {
    const int stp = tid >> 3;           // 0..63 step offset within chunk
    const int rb  = (tid & 7) * 8;      // row offset base within block
    int g = cb0 + stp; if (g > TT - 1) g = TT - 1;
    const char* base = (const char*)noise + (size_t)g * (NN * 2 * 4);
    u32x4 v[4];
#pragma unroll
    for (int i = 0; i < 4; ++i) {
        int row = blk * NROW + rb + 2 * i;
        if (row > NN - 2) row = NN - 2;          // clamp: stay in-bounds (pad rows unused)
        v[i] = *(const u32x4*)(base + (size_t)row * 8);
    }
#pragma unroll
    for (int i = 0; i < 4; ++i)
        *(u32x4*)&nbuf[stp][rb + 2 * i] = v[i];
}

__global__ __launch_bounds__(TPB) void hopf_main(
    const float* __restrict__ sc, const float* __restrict__ x0,
    const float* __restrict__ y0, const float* __restrict__ aa,
    const float* __restrict__ om, const float* __restrict__ noise,
    const float* __restrict__ gg, float* __restrict__ out,
    u32x4* __restrict__ pub)
{
    const int tid  = threadIdx.x;
    const int blk  = blockIdx.x;
    const int cgrp = tid & 31;       // 32 column groups
    const int rgrp = tid >> 5;       // 16 row groups of RPT rows
    const int r0   = blk * NROW + rgrp * RPT;   // padded global row base

    __shared__ __align__(16) float2 xy[2][NPAD];        // double-buffered state
    __shared__ __align__(16) float2 nbuf[2][CHUNK][64]; // noise chunks (64 KB)

    // ---- sc slice -> registers.  col(c) = cgrp + 32*c ----
    float scr[RPT][CPT];
#pragma unroll
    for (int r = 0; r < RPT; ++r) {
        int row = r0 + r;
#pragma unroll
        for (int c = 0; c < CPT; ++c) {
            int col = cgrp + 32 * c;
            scr[r][c] = (row < NN && col < NN) ? sc[row * NN + col] : 0.0f;
        }
    }

    // ---- deg per row ----
    float dsum[RPT];
#pragma unroll
    for (int r = 0; r < RPT; ++r) {
        float s = 0.f;
#pragma unroll
        for (int c = 0; c < CPT; ++c) s += scr[r][c];
        dsum[r] = s;
    }
#pragma unroll
    for (int m = 16; m >= 1; m >>= 1) {
#pragma unroll
        for (int r = 0; r < RPT; ++r) dsum[r] += __shfl_xor(dsum[r], m, 32);
    }

    // ---- pin the sc slice (optimizer cannot demote/rematerialize) ----
#pragma unroll
    for (int r = 0; r < RPT; ++r)
#pragma unroll
        for (int c = 0; c < CPT; ++c)
            asm volatile("" : "+v"(scr[r][c]));

    // ---- per-finalize-lane constants (lanes cgrp<RPT own row r0+cgrp) ----
    float a_i = 0.f, om_i = 0.f, deg_i = 0.f;
    int myrow = -1;
    if (cgrp < RPT) {
        int row = r0 + cgrp;
        deg_i = (cgrp == 0) ? dsum[0] : (cgrp == 1) ? dsum[1]
              : (cgrp == 2) ? dsum[2] : dsum[3];
        if (row < NN) { myrow = row; a_i = aa[row]; om_i = om[row]; }
    }
    const float g = gg[0];
    const int ri = rgrp * RPT + cgrp;   // row-in-block for noise reads (valid when myrow>=0)

    // ---- initial state into LDS + first noise chunk ----
    if (tid < NPAD) {
        xy[0][tid] = (tid < NN) ? make_float2(x0[tid], y0[tid]) : make_float2(0.f, 0.f);
        xy[1][tid] = make_float2(0.f, 0.f);
    }
    load_noise_chunk(noise, blk, tid, 0, nbuf[0]);
    __syncthreads();

    for (int t = 0; t < TT; ++t) {
        const int p  = t & 1;
        const int so = t & (CHUNK - 1);
        const int cb = (t >> 6) & 1;

        // per-step noise from LDS (lgkmcnt only — never drained by the poll)
        float2 nz = make_float2(0.f, 0.f);
        if (myrow >= 0) nz = nbuf[cb][so][ri];

        // ---- partial matvec: 4 rows x 16 strided cols per thread ----
        float2 acc[RPT];
#pragma unroll
        for (int r = 0; r < RPT; ++r) acc[r] = make_float2(0.f, 0.f);
#pragma unroll
        for (int c = 0; c < CPT; ++c) {
            float2 w = xy[p][cgrp + 32 * c];
#pragma unroll
            for (int r = 0; r < RPT; ++r) {
                acc[r].x += scr[r][c] * w.x;
                acc[r].y += scr[r][c] * w.y;
            }
        }
        // ---- reduce across the 32 column-group lanes ----
#pragma unroll
        for (int m = 16; m >= 1; m >>= 1) {
#pragma unroll
            for (int r = 0; r < RPT; ++r) {
                acc[r].x += __shfl_xor(acc[r].x, m, 32);
                acc[r].y += __shfl_xor(acc[r].y, m, 32);
            }
        }

        // ---- finalize + publish tagged 16B packet (lanes cgrp<RPT) ----
        float xn = 0.f;
        if (myrow >= 0) {
            float sx = (cgrp == 0) ? acc[0].x : (cgrp == 1) ? acc[1].x
                     : (cgrp == 2) ? acc[2].x : acc[3].x;
            float sy = (cgrp == 0) ? acc[0].y : (cgrp == 1) ? acc[1].y
                     : (cgrp == 2) ? acc[2].y : acc[3].y;
            float2 cur = xy[p][myrow];
            float r2 = cur.x * cur.x + cur.y * cur.y;
            float cx = sx - deg_i * cur.x;
            float cy = sy - deg_i * cur.y;
            float dx = (a_i - r2) * cur.x - om_i * cur.y + g * cx;
            float dy = (a_i - r2) * cur.y + om_i * cur.x + g * cy;
            xn = cur.x + DTC * dx + SQDTC * nz.x;
            float yn = cur.y + DTC * dy + SQDTC * nz.y;
            u32x4 pkt = { __float_as_uint(xn), (unsigned)(t + 1),
                          __float_as_uint(yn), (unsigned)(t + 1) };
            store_coh_u128(&pub[(size_t)p * NPAD + myrow], pkt);
        }

        if (t == TT - 1) {                       // uniform across grid
            if (myrow >= 0) out[(size_t)t * NN + myrow] = xn;
            break;
        }

        // ---- gather: single-outstanding poll of own tagged slot.
        //      vmem stream here = {pub store, poll loads} only. ----
        u32x4 va;
        if (tid < NN) {
            const u32x4* slot = &pub[(size_t)p * NPAD + tid];
            do {
                va = load_coh_u128(slot);
            } while ((int)va.y < t + 1 || (int)va.w < t + 1);
        }

        // out store post-poll: ack hidden under next step's matvec
        if (myrow >= 0) out[(size_t)t * NN + myrow] = xn;

        if (tid < NN)
            xy[p ^ 1][tid] = make_float2(__uint_as_float(va.x), __uint_as_float(va.z));

        // ---- chunk boundary: stage next 64 steps of noise (1 RTT / 64 steps) ----
        if (so == CHUNK - 1)
            load_noise_chunk(noise, blk, tid, t + 1, nbuf[cb ^ 1]);

        __syncthreads();
    }
}

extern "C" void kernel_launch(void* const* d_in, const int* in_sizes, int n_in,
                              void* d_out, int out_size, void* d_ws, size_t ws_size,
                              hipStream_t stream) {
    const float* sc = (const float*)d_in[0];
    const float* x0 = (const float*)d_in[1];
    const float* y0 = (const float*)d_in[2];
    const float* aa = (const float*)d_in[3];
    const float* om = (const float*)d_in[4];
    const float* nz = (const float*)d_in[5];
    const float* gg = (const float*)d_in[6];
    float* out = (float*)d_out;

    u32x4* pub = (u32x4*)d_ws;   // 2*NPAD*16 = 16 KB

    hipLaunchKernelGGL(hopf_init_ws, dim3(1), dim3(1024), 0, stream, pub);
    hipLaunchKernelGGL(hopf_main, dim3(NBLK), dim3(TPB), 0, stream,
                       sc, x0, y0, aa, om, nz, gg, out, pub);
}